// Round 1
// baseline (1075.734 us; speedup 1.0000x reference)
//
#include <hip/hip_runtime.h>
#include <hip/hip_bf16.h>

// GCN 3-layer + MLP head for anomaly_anticipation.
// Strategy: build CSR (by row) once per launch, then per-layer:
//   h = x @ W  (fp32 tiled GEMM, 64x64 tile)
//   out[i] = relu( sum_{e in row(i)} h[col(e)] * norm(e) + b )   (gather, no atomics)
// Final: fused 2-layer MLP per node.

#define WG 256

// ---------------- graph build ----------------

__global__ void count_kernel(const int* __restrict__ row, int* __restrict__ cnt, int E) {
    int e = blockIdx.x * blockDim.x + threadIdx.x;
    if (e < E) atomicAdd(&cnt[row[e]], 1);
}

__global__ void dis_kernel(const int* __restrict__ cnt, float* __restrict__ dis, int n) {
    int i = blockIdx.x * blockDim.x + threadIdx.x;
    if (i < n) {
        float d = (float)(cnt[i] + 1);   // +1 self-loop; always > 0
        dis[i] = 1.0f / sqrtf(d);
    }
}

// exclusive scan of (cnt[i]+1) -> rowstart[0..n], single block of 1024 threads
__global__ __launch_bounds__(1024) void scan_kernel(const int* __restrict__ cnt,
                                                    int* __restrict__ rowstart, int n) {
    __shared__ int buf[1024];
    const int tid = threadIdx.x;
    if (tid == 0) rowstart[0] = 0;
    int running = 0;
    for (int base = 0; base < n; base += 1024) {
        int i = base + tid;
        int v = (i < n) ? (cnt[i] + 1) : 0;
        buf[tid] = v;
        __syncthreads();
        // Hillis-Steele inclusive scan
        for (int off = 1; off < 1024; off <<= 1) {
            int t = (tid >= off) ? buf[tid - off] : 0;
            __syncthreads();
            buf[tid] += t;
            __syncthreads();
        }
        if (i < n) rowstart[i + 1] = running + buf[tid];
        __syncthreads();
        running += buf[1023];
        __syncthreads();
    }
}

// self-loop goes in slot 0 of each node's segment; fill starts at 1
__global__ void selfloop_kernel(const int* __restrict__ rowstart, const float* __restrict__ dis,
                                int* __restrict__ edge_dst, float* __restrict__ edge_norm,
                                int* __restrict__ fill, int n) {
    int i = blockIdx.x * blockDim.x + threadIdx.x;
    if (i < n) {
        int p = rowstart[i];
        edge_dst[p] = i;
        float d = dis[i];
        edge_norm[p] = d * d;
        fill[i] = 1;
    }
}

__global__ void scatter_kernel(const int* __restrict__ row, const int* __restrict__ col,
                               const int* __restrict__ rowstart, const float* __restrict__ dis,
                               int* __restrict__ edge_dst, float* __restrict__ edge_norm,
                               int* __restrict__ fill, int E) {
    int e = blockIdx.x * blockDim.x + threadIdx.x;
    if (e < E) {
        int r = row[e], c = col[e];
        int pos = rowstart[r] + atomicAdd(&fill[r], 1);
        edge_dst[pos] = c;
        edge_norm[pos] = dis[r] * dis[c];
    }
}

// ---------------- fp32 tiled GEMM: C[M,N] = A[M,K] * B[K,N] ----------------

__global__ __launch_bounds__(256) void gemm_kernel(const float* __restrict__ A,
                                                   const float* __restrict__ B,
                                                   float* __restrict__ C,
                                                   int M, int N, int K) {
    __shared__ float As[16][65];   // As[k][m]
    __shared__ float Bs[16][65];   // Bs[k][n]
    const int tid  = threadIdx.x;
    const int trow = tid >> 4;     // 0..15
    const int tcol = tid & 15;     // 0..15
    const int m0 = blockIdx.y * 64;
    const int n0 = blockIdx.x * 64;
    float acc[4][4] = {{0.f}};
    for (int k0 = 0; k0 < K; k0 += 16) {
        #pragma unroll
        for (int i = 0; i < 4; ++i) {            // A tile 64m x 16k
            int idx = i * 256 + tid;
            int k = idx & 15, m = idx >> 4;
            int gm = m0 + m, gk = k0 + k;
            As[k][m] = (gm < M && gk < K) ? A[gm * K + gk] : 0.f;
        }
        #pragma unroll
        for (int i = 0; i < 4; ++i) {            // B tile 16k x 64n
            int idx = i * 256 + tid;
            int n = idx & 63, k = idx >> 6;
            int gn = n0 + n, gk = k0 + k;
            Bs[k][n] = (gn < N && gk < K) ? B[gk * N + gn] : 0.f;
        }
        __syncthreads();
        #pragma unroll
        for (int k = 0; k < 16; ++k) {
            float a[4], b[4];
            #pragma unroll
            for (int i = 0; i < 4; ++i) a[i] = As[k][trow * 4 + i];
            #pragma unroll
            for (int j = 0; j < 4; ++j) b[j] = Bs[k][tcol * 4 + j];
            #pragma unroll
            for (int i = 0; i < 4; ++i)
                #pragma unroll
                for (int j = 0; j < 4; ++j)
                    acc[i][j] += a[i] * b[j];
        }
        __syncthreads();
    }
    #pragma unroll
    for (int i = 0; i < 4; ++i) {
        int gm = m0 + trow * 4 + i;
        if (gm >= M) continue;
        #pragma unroll
        for (int j = 0; j < 4; ++j) {
            int gn = n0 + tcol * 4 + j;
            if (gn < N) C[gm * N + gn] = acc[i][j];
        }
    }
}

// ---------------- CSR gather aggregation: out = relu(Agg(h)*norm + b) ----------------

template <int NF>
__global__ __launch_bounds__(64) void agg_kernel(const float* __restrict__ h,
                                                 const int* __restrict__ rowstart,
                                                 const int* __restrict__ edge_dst,
                                                 const float* __restrict__ edge_norm,
                                                 const float* __restrict__ bias,
                                                 float* __restrict__ out, int F, int relu) {
    const int node = blockIdx.x;
    const int start = rowstart[node], end = rowstart[node + 1];
    float acc[NF];
    #pragma unroll
    for (int j = 0; j < NF; ++j) acc[j] = 0.f;
    for (int e = start; e < end; ++e) {
        int c = edge_dst[e];
        float w = edge_norm[e];
        const float* hr = h + c * F;
        #pragma unroll
        for (int j = 0; j < NF; ++j) {
            int f = threadIdx.x + j * 64;
            if (f < F) acc[j] += hr[f] * w;
        }
    }
    #pragma unroll
    for (int j = 0; j < NF; ++j) {
        int f = threadIdx.x + j * 64;
        if (f < F) {
            float v = acc[j] + bias[f];
            if (relu) v = fmaxf(v, 0.f);
            out[node * F + f] = v;
        }
    }
}

// ---------------- fused final MLP: out = (a3 @ Wf1 + bf1) @ Wf2 + bf2 ----------------

__global__ void final_kernel(const float* __restrict__ a3,
                             const float* __restrict__ Wf1, const float* __restrict__ bf1,
                             const float* __restrict__ Wf2, const float* __restrict__ bf2,
                             float* __restrict__ out, int n, int C, int H) {
    int i = blockIdx.x * blockDim.x + threadIdx.x;
    if (i >= n) return;
    const float* xr = a3 + i * C;
    float hbuf[16];
    for (int j = 0; j < H; ++j) hbuf[j] = bf1[j];
    for (int k = 0; k < C; ++k) {
        float xv = xr[k];
        for (int j = 0; j < H; ++j) hbuf[j] += xv * Wf1[k * H + j];
    }
    float o = bf2[0];
    for (int j = 0; j < H; ++j) o += hbuf[j] * Wf2[j];
    out[i] = o;
}

// ---------------- launch ----------------

extern "C" void kernel_launch(void* const* d_in, const int* in_sizes, int n_in,
                              void* d_out, int out_size, void* d_ws, size_t ws_size,
                              hipStream_t stream) {
    const float* x   = (const float*)d_in[0];
    const int*   ei  = (const int*)d_in[1];
    const float* W1  = (const float*)d_in[2];
    const float* b1  = (const float*)d_in[3];
    const float* W2  = (const float*)d_in[4];
    const float* b2  = (const float*)d_in[5];
    const float* W3  = (const float*)d_in[6];
    const float* b3  = (const float*)d_in[7];
    const float* Wf1 = (const float*)d_in[8];
    const float* bf1 = (const float*)d_in[9];
    const float* Wf2 = (const float*)d_in[10];
    const float* bf2 = (const float*)d_in[11];
    float* out = (float*)d_out;

    const int N    = out_size;                 // 50000
    const int E    = in_sizes[1] / 2;          // 800000
    const int IN_C = in_sizes[0] / N;          // 256
    const int H1   = in_sizes[3];              // 300
    const int H2   = in_sizes[5];              // 100
    const int OUTC = in_sizes[7];              // 32
    const int F1   = in_sizes[9];              // 16
    const int EL   = E + N;                    // with self-loops

    const int* row = ei;
    const int* col = ei + E;

    // workspace layout (256B aligned)
    size_t off = 0;
    auto alloc = [&](size_t bytes) {
        size_t o = off;
        off += (bytes + 255) & ~(size_t)255;
        return o;
    };
    char* ws = (char*)d_ws;
    int*   cnt      = (int*)  (ws + alloc((size_t)N * 4));
    int*   fill     = (int*)  (ws + alloc((size_t)N * 4));
    float* dis      = (float*)(ws + alloc((size_t)N * 4));
    int*   rowstart = (int*)  (ws + alloc((size_t)(N + 1) * 4));
    int*   edge_dst = (int*)  (ws + alloc((size_t)EL * 4));
    float* edge_nrm = (float*)(ws + alloc((size_t)EL * 4));
    float* bufA     = (float*)(ws + alloc((size_t)N * H1 * 4));   // h1; later h2/a2/h3
    float* bufB     = (float*)(ws + alloc((size_t)N * H1 * 4));   // a1; later a3

    float* h1 = bufA;
    float* a1 = bufB;
    float* h2 = bufA;                    // N*H2
    float* a2 = bufA + (size_t)N * H2;   // N*H2
    float* h3 = bufA + (size_t)2 * N * H2; // N*OUTC
    float* a3 = bufB;                    // N*OUTC

    const int gN = (N + WG - 1) / WG;
    const int gE = (E + WG - 1) / WG;

    // --- build CSR ---
    hipMemsetAsync(cnt, 0, (size_t)N * 4, stream);
    count_kernel<<<gE, WG, 0, stream>>>(row, cnt, E);
    dis_kernel<<<gN, WG, 0, stream>>>(cnt, dis, N);
    scan_kernel<<<1, 1024, 0, stream>>>(cnt, rowstart, N);
    selfloop_kernel<<<gN, WG, 0, stream>>>(rowstart, dis, edge_dst, edge_nrm, fill, N);
    scatter_kernel<<<gE, WG, 0, stream>>>(row, col, rowstart, dis, edge_dst, edge_nrm, fill, E);

    // --- layer 1: [N,256] @ [256,300] ---
    {
        dim3 grid((H1 + 63) / 64, (N + 63) / 64);
        gemm_kernel<<<grid, 256, 0, stream>>>(x, W1, h1, N, H1, IN_C);
        agg_kernel<5><<<N, 64, 0, stream>>>(h1, rowstart, edge_dst, edge_nrm, b1, a1, H1, 1);
    }
    // --- layer 2: [N,300] @ [300,100] ---
    {
        dim3 grid((H2 + 63) / 64, (N + 63) / 64);
        gemm_kernel<<<grid, 256, 0, stream>>>(a1, W2, h2, N, H2, H1);
        agg_kernel<2><<<N, 64, 0, stream>>>(h2, rowstart, edge_dst, edge_nrm, b2, a2, H2, 1);
    }
    // --- layer 3: [N,100] @ [100,32] ---
    {
        dim3 grid((OUTC + 63) / 64, (N + 63) / 64);
        gemm_kernel<<<grid, 256, 0, stream>>>(a2, W3, h3, N, OUTC, H2);
        agg_kernel<1><<<N, 64, 0, stream>>>(h3, rowstart, edge_dst, edge_nrm, b3, a3, OUTC, 1);
    }
    // --- final MLP ---
    final_kernel<<<gN, WG, 0, stream>>>(a3, Wf1, bf1, Wf2, bf2, out, N, OUTC, F1);
}

// Round 2
// 785.580 us; speedup vs baseline: 1.3694x; 1.3694x over previous
//
#include <hip/hip_runtime.h>
#include <hip/hip_bf16.h>

// GCN 3-layer + MLP head.
// This round: replace fp32 SIMD GEMM with split-bf16 (hi+lo) MFMA GEMM.
//   C = Ahi@Bhi + Ahi@Blo + Alo@Bhi  (3x mfma_f32_16x16x32_bf16, fp32-accurate)
// A conversion fused into LDS staging; B pre-converted to fragment layout.

#define WG 256

typedef __attribute__((ext_vector_type(4))) float f32x4;
typedef __attribute__((ext_vector_type(8))) short bf16x8;
typedef __attribute__((ext_vector_type(4))) unsigned short u16x4;

__device__ inline unsigned short f2bf(float v) {
    union { float f; unsigned u; } c; c.f = v;
    unsigned r = (c.u + 0x7fff + ((c.u >> 16) & 1)) >> 16;   // RNE
    return (unsigned short)r;
}
__device__ inline float bf2f(unsigned short h) {
    union { unsigned u; float f; } c; c.u = ((unsigned)h) << 16;
    return c.f;
}

// ---------------- graph build ----------------

__global__ void count_kernel(const int* __restrict__ row, int* __restrict__ cnt, int E) {
    int e = blockIdx.x * blockDim.x + threadIdx.x;
    if (e < E) atomicAdd(&cnt[row[e]], 1);
}

__global__ void dis_kernel(const int* __restrict__ cnt, float* __restrict__ dis, int n) {
    int i = blockIdx.x * blockDim.x + threadIdx.x;
    if (i < n) {
        float d = (float)(cnt[i] + 1);
        dis[i] = 1.0f / sqrtf(d);
    }
}

__global__ __launch_bounds__(1024) void scan_kernel(const int* __restrict__ cnt,
                                                    int* __restrict__ rowstart, int n) {
    __shared__ int buf[1024];
    const int tid = threadIdx.x;
    if (tid == 0) rowstart[0] = 0;
    int running = 0;
    for (int base = 0; base < n; base += 1024) {
        int i = base + tid;
        int v = (i < n) ? (cnt[i] + 1) : 0;
        buf[tid] = v;
        __syncthreads();
        for (int off = 1; off < 1024; off <<= 1) {
            int t = (tid >= off) ? buf[tid - off] : 0;
            __syncthreads();
            buf[tid] += t;
            __syncthreads();
        }
        if (i < n) rowstart[i + 1] = running + buf[tid];
        __syncthreads();
        running += buf[1023];
        __syncthreads();
    }
}

__global__ void selfloop_kernel(const int* __restrict__ rowstart, const float* __restrict__ dis,
                                int* __restrict__ edge_dst, float* __restrict__ edge_norm,
                                int* __restrict__ fill, int n) {
    int i = blockIdx.x * blockDim.x + threadIdx.x;
    if (i < n) {
        int p = rowstart[i];
        edge_dst[p] = i;
        float d = dis[i];
        edge_norm[p] = d * d;
        fill[i] = 1;
    }
}

__global__ void scatter_kernel(const int* __restrict__ row, const int* __restrict__ col,
                               const int* __restrict__ rowstart, const float* __restrict__ dis,
                               int* __restrict__ edge_dst, float* __restrict__ edge_norm,
                               int* __restrict__ fill, int E) {
    int e = blockIdx.x * blockDim.x + threadIdx.x;
    if (e < E) {
        int r = row[e], c = col[e];
        int pos = rowstart[r] + atomicAdd(&fill[r], 1);
        edge_dst[pos] = c;
        edge_norm[pos] = dis[r] * dis[c];
    }
}

// ---------------- weight conversion: W[K,N] fp32 -> frag layout [Kpad/8][Npad][8] bf16 hi/lo ----------------

__global__ void convB_kernel(const float* __restrict__ W,
                             unsigned short* __restrict__ bth, unsigned short* __restrict__ btl,
                             int K, int N, int Kpad, int Npad) {
    int idx = blockIdx.x * blockDim.x + threadIdx.x;
    int total = (Kpad / 8) * Npad * 8;
    if (idx >= total) return;
    int i = idx & 7;
    int rest = idx >> 3;
    int n = rest % Npad;
    int qg = rest / Npad;
    int k = qg * 8 + i;
    float v = (k < K && n < N) ? W[k * N + n] : 0.f;
    unsigned short h = f2bf(v);
    unsigned short l = f2bf(v - bf2f(h));
    bth[idx] = h;
    btl[idx] = l;
}

// ---------------- split-bf16 MFMA GEMM ----------------
// C[M, Npad] = A[M, K] @ B  (B pre-converted). Tile 128x64, 4 waves, K-step 32.
// LDS A layout: [q=4][m=128][8 bf16] (fragment-ready, conflict-free b128 reads).

__global__ __launch_bounds__(256) void mfma_gemm(const float* __restrict__ A,
                                                 const unsigned short* __restrict__ Bth,
                                                 const unsigned short* __restrict__ Btl,
                                                 float* __restrict__ C,
                                                 int M, int K, int Kpad, int Npad) {
    __shared__ unsigned short Ah[4 * 128 * 8];
    __shared__ unsigned short Al[4 * 128 * 8];
    const int tid  = threadIdx.x;
    const int lane = tid & 63;
    const int wid  = tid >> 6;
    const int wm   = (wid >> 1) * 64;    // wave row offset in tile
    const int wn   = (wid & 1) * 32;     // wave col offset in tile
    const int m0   = blockIdx.y * 128;
    const int n0   = blockIdx.x * 64;
    const int q    = lane >> 4;          // 0..3
    const int lr   = lane & 15;

    f32x4 acc[4][2];
    #pragma unroll
    for (int i = 0; i < 4; ++i)
        #pragma unroll
        for (int j = 0; j < 2; ++j) {
            f32x4 z = {0.f, 0.f, 0.f, 0.f};
            acc[i][j] = z;
        }

    f32x4 rg[4];

    auto load_tile = [&](int k0) {
        #pragma unroll
        for (int it = 0; it < 4; ++it) {
            int lin = it * 256 + tid;     // 0..1023
            int r   = lin >> 3;           // row in tile 0..127
            int f4  = lin & 7;            // float4 index 0..7
            int row = m0 + r;
            int k   = k0 + f4 * 4;
            f32x4 v = {0.f, 0.f, 0.f, 0.f};
            if (row < M) {
                if (k + 4 <= K) {
                    v = *(const f32x4*)(A + (size_t)row * K + k);
                } else {
                    #pragma unroll
                    for (int e = 0; e < 4; ++e)
                        if (k + e < K) v[e] = A[(size_t)row * K + k + e];
                }
            }
            rg[it] = v;
        }
    };

    auto write_stage = [&]() {
        #pragma unroll
        for (int it = 0; it < 4; ++it) {
            int lin  = it * 256 + tid;
            int r    = lin >> 3;
            int f4   = lin & 7;
            int qq   = f4 >> 1;
            int half = f4 & 1;
            u16x4 hi, lo;
            #pragma unroll
            for (int e = 0; e < 4; ++e) {
                float v = rg[it][e];
                unsigned short h = f2bf(v);
                hi[e] = h;
                lo[e] = f2bf(v - bf2f(h));
            }
            int off = (qq * 128 + r) * 8 + half * 4;   // ushort units
            *(u16x4*)(Ah + off) = hi;
            *(u16x4*)(Al + off) = lo;
        }
    };

    load_tile(0);
    const int nk = Kpad >> 5;
    for (int t = 0; t < nk; ++t) {
        if (t) __syncthreads();
        write_stage();
        __syncthreads();
        if (t + 1 < nk) load_tile((t + 1) * 32);

        bf16x8 ah[4], al[4];
        #pragma unroll
        for (int mf = 0; mf < 4; ++mf) {
            int off = (q * 128 + wm + mf * 16 + lr) * 8;
            ah[mf] = *(const bf16x8*)(Ah + off);
            al[mf] = *(const bf16x8*)(Al + off);
        }
        bf16x8 bh[2], bl[2];
        int qg = t * 4 + q;
        #pragma unroll
        for (int nf = 0; nf < 2; ++nf) {
            int n = n0 + wn + nf * 16 + lr;
            size_t coff = ((size_t)qg * Npad + n) * 8;
            bh[nf] = *(const bf16x8*)(Bth + coff);
            bl[nf] = *(const bf16x8*)(Btl + coff);
        }
        #pragma unroll
        for (int mf = 0; mf < 4; ++mf)
            #pragma unroll
            for (int nf = 0; nf < 2; ++nf)
                acc[mf][nf] = __builtin_amdgcn_mfma_f32_16x16x32_bf16(ah[mf], bh[nf], acc[mf][nf], 0, 0, 0);
        #pragma unroll
        for (int mf = 0; mf < 4; ++mf)
            #pragma unroll
            for (int nf = 0; nf < 2; ++nf)
                acc[mf][nf] = __builtin_amdgcn_mfma_f32_16x16x32_bf16(ah[mf], bl[nf], acc[mf][nf], 0, 0, 0);
        #pragma unroll
        for (int mf = 0; mf < 4; ++mf)
            #pragma unroll
            for (int nf = 0; nf < 2; ++nf)
                acc[mf][nf] = __builtin_amdgcn_mfma_f32_16x16x32_bf16(al[mf], bh[nf], acc[mf][nf], 0, 0, 0);
    }

    // epilogue: C/D layout col = lane&15, row = (lane>>4)*4 + reg (guide-verified)
    #pragma unroll
    for (int mf = 0; mf < 4; ++mf) {
        int row_base = m0 + wm + mf * 16 + (lane >> 4) * 4;
        #pragma unroll
        for (int nf = 0; nf < 2; ++nf) {
            int col = n0 + wn + nf * 16 + lr;
            #pragma unroll
            for (int r = 0; r < 4; ++r) {
                int row = row_base + r;
                if (row < M) C[(size_t)row * Npad + col] = acc[mf][nf][r];
            }
        }
    }
}

// ---------------- CSR gather aggregation: out = relu(Agg(h)*norm + b) ----------------

template <int NF>
__global__ __launch_bounds__(64) void agg_kernel(const float* __restrict__ h,
                                                 const int* __restrict__ rowstart,
                                                 const int* __restrict__ edge_dst,
                                                 const float* __restrict__ edge_norm,
                                                 const float* __restrict__ bias,
                                                 float* __restrict__ out,
                                                 int F, int stride, int relu) {
    const int node = blockIdx.x;
    const int start = rowstart[node], end = rowstart[node + 1];
    float acc[NF];
    #pragma unroll
    for (int j = 0; j < NF; ++j) acc[j] = 0.f;
    for (int e = start; e < end; ++e) {
        int c = edge_dst[e];
        float w = edge_norm[e];
        const float* hr = h + (size_t)c * stride;
        #pragma unroll
        for (int j = 0; j < NF; ++j) {
            int f = threadIdx.x + j * 64;
            if (f < F) acc[j] += hr[f] * w;
        }
    }
    #pragma unroll
    for (int j = 0; j < NF; ++j) {
        int f = threadIdx.x + j * 64;
        if (f < F) {
            float v = acc[j] + bias[f];
            if (relu) v = fmaxf(v, 0.f);
            out[(size_t)node * F + f] = v;
        }
    }
}

// ---------------- fused final MLP ----------------

__global__ void final_kernel(const float* __restrict__ a3,
                             const float* __restrict__ Wf1, const float* __restrict__ bf1,
                             const float* __restrict__ Wf2, const float* __restrict__ bf2,
                             float* __restrict__ out, int n, int C, int H) {
    int i = blockIdx.x * blockDim.x + threadIdx.x;
    if (i >= n) return;
    const float* xr = a3 + (size_t)i * C;
    float hbuf[16];
    for (int j = 0; j < H; ++j) hbuf[j] = bf1[j];
    for (int k = 0; k < C; ++k) {
        float xv = xr[k];
        for (int j = 0; j < H; ++j) hbuf[j] += xv * Wf1[k * H + j];
    }
    float o = bf2[0];
    for (int j = 0; j < H; ++j) o += hbuf[j] * Wf2[j];
    out[i] = o;
}

// ---------------- launch ----------------

extern "C" void kernel_launch(void* const* d_in, const int* in_sizes, int n_in,
                              void* d_out, int out_size, void* d_ws, size_t ws_size,
                              hipStream_t stream) {
    const float* x   = (const float*)d_in[0];
    const int*   ei  = (const int*)d_in[1];
    const float* W1  = (const float*)d_in[2];
    const float* b1  = (const float*)d_in[3];
    const float* W2  = (const float*)d_in[4];
    const float* b2  = (const float*)d_in[5];
    const float* W3  = (const float*)d_in[6];
    const float* b3  = (const float*)d_in[7];
    const float* Wf1 = (const float*)d_in[8];
    const float* bf1 = (const float*)d_in[9];
    const float* Wf2 = (const float*)d_in[10];
    const float* bf2 = (const float*)d_in[11];
    float* out = (float*)d_out;

    const int N    = out_size;                 // 50000
    const int E    = in_sizes[1] / 2;          // 800000
    const int IN_C = in_sizes[0] / N;          // 256
    const int H1   = in_sizes[3];              // 300
    const int H2   = in_sizes[5];              // 100
    const int OUTC = in_sizes[7];              // 32
    const int F1   = in_sizes[9];              // 16
    const int EL   = E + N;

    // padded dims
    const int KP1 = 256, NP1 = 320;            // layer1: K=256, N=300
    const int KP2 = 320, NP2 = 128;            // layer2: K=300, N=100
    const int KP3 = 128, NP3 = 64;             // layer3: K=100, N=32

    const int* row = ei;
    const int* col = ei + E;

    size_t off = 0;
    auto alloc = [&](size_t bytes) {
        size_t o = off;
        off += (bytes + 255) & ~(size_t)255;
        return o;
    };
    char* ws = (char*)d_ws;
    int*   cnt      = (int*)  (ws + alloc((size_t)N * 4));
    int*   fill     = (int*)  (ws + alloc((size_t)N * 4));
    float* dis      = (float*)(ws + alloc((size_t)N * 4));
    int*   rowstart = (int*)  (ws + alloc((size_t)(N + 1) * 4));
    int*   edge_dst = (int*)  (ws + alloc((size_t)EL * 4));
    float* edge_nrm = (float*)(ws + alloc((size_t)EL * 4));
    unsigned short* Bt1h = (unsigned short*)(ws + alloc((size_t)(KP1/8) * NP1 * 8 * 2));
    unsigned short* Bt1l = (unsigned short*)(ws + alloc((size_t)(KP1/8) * NP1 * 8 * 2));
    unsigned short* Bt2h = (unsigned short*)(ws + alloc((size_t)(KP2/8) * NP2 * 8 * 2));
    unsigned short* Bt2l = (unsigned short*)(ws + alloc((size_t)(KP2/8) * NP2 * 8 * 2));
    unsigned short* Bt3h = (unsigned short*)(ws + alloc((size_t)(KP3/8) * NP3 * 8 * 2));
    unsigned short* Bt3l = (unsigned short*)(ws + alloc((size_t)(KP3/8) * NP3 * 8 * 2));
    float* bufH = (float*)(ws + alloc((size_t)N * NP1 * 4));   // 64 MB arena
    float* a1   = (float*)(ws + alloc((size_t)N * H1 * 4));    // 60 MB

    float* h1 = bufH;                                  // [N,320]
    float* h2 = bufH;                                  // [N,128]   (h1 dead)
    float* a2 = bufH + (size_t)N * NP2;                // [N,100]
    float* h3 = bufH + (size_t)N * (NP2 + H2);         // [N,64]
    float* a3 = bufH;                                  // [N,32]    (h2 dead)

    const int gN = (N + WG - 1) / WG;
    const int gE = (E + WG - 1) / WG;

    // --- build CSR ---
    hipMemsetAsync(cnt, 0, (size_t)N * 4, stream);
    count_kernel<<<gE, WG, 0, stream>>>(row, cnt, E);
    dis_kernel<<<gN, WG, 0, stream>>>(cnt, dis, N);
    scan_kernel<<<1, 1024, 0, stream>>>(cnt, rowstart, N);
    selfloop_kernel<<<gN, WG, 0, stream>>>(rowstart, dis, edge_dst, edge_nrm, fill, N);
    scatter_kernel<<<gE, WG, 0, stream>>>(row, col, rowstart, dis, edge_dst, edge_nrm, fill, E);

    // --- convert weights ---
    {
        int t1 = (KP1/8) * NP1 * 8;
        convB_kernel<<<(t1 + WG - 1) / WG, WG, 0, stream>>>(W1, Bt1h, Bt1l, IN_C, H1, KP1, NP1);
        int t2 = (KP2/8) * NP2 * 8;
        convB_kernel<<<(t2 + WG - 1) / WG, WG, 0, stream>>>(W2, Bt2h, Bt2l, H1, H2, KP2, NP2);
        int t3 = (KP3/8) * NP3 * 8;
        convB_kernel<<<(t3 + WG - 1) / WG, WG, 0, stream>>>(W3, Bt3h, Bt3l, H2, OUTC, KP3, NP3);
    }

    const int MB = (N + 127) / 128;

    // --- layer 1 ---
    mfma_gemm<<<dim3(NP1 / 64, MB), 256, 0, stream>>>(x, Bt1h, Bt1l, h1, N, IN_C, KP1, NP1);
    agg_kernel<5><<<N, 64, 0, stream>>>(h1, rowstart, edge_dst, edge_nrm, b1, a1, H1, NP1, 1);
    // --- layer 2 ---
    mfma_gemm<<<dim3(NP2 / 64, MB), 256, 0, stream>>>(a1, Bt2h, Bt2l, h2, N, H1, KP2, NP2);
    agg_kernel<2><<<N, 64, 0, stream>>>(h2, rowstart, edge_dst, edge_nrm, b2, a2, H2, NP2, 1);
    // --- layer 3 ---
    mfma_gemm<<<dim3(NP3 / 64, MB), 256, 0, stream>>>(a2, Bt3h, Bt3l, h3, N, H2, KP3, NP3);
    agg_kernel<1><<<N, 64, 0, stream>>>(h3, rowstart, edge_dst, edge_nrm, b3, a3, OUTC, NP3, 1);
    // --- final MLP ---
    final_kernel<<<gN, WG, 0, stream>>>(a3, Wf1, bf1, Wf2, bf2, out, N, OUTC, F1);
}

// Round 9
// 591.686 us; speedup vs baseline: 1.8181x; 1.3277x over previous
//
#include <hip/hip_runtime.h>
#include <hip/hip_bf16.h>

// GCN 3-layer + MLP head.
// Round 3 (6th resubmit — bench infra timeouts): restructure aggregation.
//  - layer1: aggregate X FIRST (agg is linear: agg(xW)= (agg x)W), 256 feats = 64 lanes x float4
//  - batched edge-index staging + shfl broadcast + 4-deep load pipeline
//  - layers 2/3: 2 / 4 edges in parallel per wave, shfl_xor cross-group reduce
//  - bias+relu for layer1 fused into GEMM1 epilogue
// GEMM: split-bf16 (hi+lo) MFMA, as round 2.

#define WG 256

typedef __attribute__((ext_vector_type(4))) float f32x4;
typedef __attribute__((ext_vector_type(8))) short bf16x8;
typedef __attribute__((ext_vector_type(4))) unsigned short u16x4;

__device__ inline unsigned short f2bf(float v) {
    union { float f; unsigned u; } c; c.f = v;
    unsigned r = (c.u + 0x7fff + ((c.u >> 16) & 1)) >> 16;   // RNE
    return (unsigned short)r;
}
__device__ inline float bf2f(unsigned short h) {
    union { unsigned u; float f; } c; c.u = ((unsigned)h) << 16;
    return c.f;
}

// ---------------- graph build ----------------

__global__ void count_kernel(const int* __restrict__ row, int* __restrict__ cnt, int E) {
    int e = blockIdx.x * blockDim.x + threadIdx.x;
    if (e < E) atomicAdd(&cnt[row[e]], 1);
}

__global__ void dis_kernel(const int* __restrict__ cnt, float* __restrict__ dis, int n) {
    int i = blockIdx.x * blockDim.x + threadIdx.x;
    if (i < n) {
        float d = (float)(cnt[i] + 1);
        dis[i] = 1.0f / sqrtf(d);
    }
}

// exclusive scan of (cnt[i]+1) -> rowstart[0..n]; single block, wave-shuffle based
__global__ __launch_bounds__(1024) void scan_kernel(const int* __restrict__ cnt,
                                                    int* __restrict__ rowstart, int n) {
    __shared__ int wsum[16];
    __shared__ int carry;
    const int tid = threadIdx.x;
    const int lane = tid & 63, wv = tid >> 6;
    if (tid == 0) { rowstart[0] = 0; carry = 0; }
    __syncthreads();
    for (int base = 0; base < n; base += 1024) {
        int i = base + tid;
        int v = (i < n) ? (cnt[i] + 1) : 0;
        int s = v;
        #pragma unroll
        for (int off = 1; off < 64; off <<= 1) {
            int t = __shfl_up(s, off);
            if (lane >= off) s += t;
        }
        if (lane == 63) wsum[wv] = s;
        __syncthreads();
        if (wv == 0 && lane < 16) {
            int ws = wsum[lane];
            int t = ws;
            #pragma unroll
            for (int off = 1; off < 16; off <<= 1) {
                int u = __shfl_up(t, off);
                if (lane >= off) t += u;
            }
            wsum[lane] = t - ws;       // exclusive wave offset
        }
        __syncthreads();
        int tp = carry;
        if (i < n) rowstart[i + 1] = tp + wsum[wv] + s;
        __syncthreads();
        if (tid == 1023) carry = tp + wsum[15] + s;
        __syncthreads();
    }
}

__global__ void selfloop_kernel(const int* __restrict__ rowstart, const float* __restrict__ dis,
                                int* __restrict__ edge_dst, float* __restrict__ edge_norm,
                                int* __restrict__ fill, int n) {
    int i = blockIdx.x * blockDim.x + threadIdx.x;
    if (i < n) {
        int p = rowstart[i];
        edge_dst[p] = i;
        float d = dis[i];
        edge_norm[p] = d * d;
        fill[i] = 1;
    }
}

__global__ void scatter_kernel(const int* __restrict__ row, const int* __restrict__ col,
                               const int* __restrict__ rowstart, const float* __restrict__ dis,
                               int* __restrict__ edge_dst, float* __restrict__ edge_norm,
                               int* __restrict__ fill, int E) {
    int e = blockIdx.x * blockDim.x + threadIdx.x;
    if (e < E) {
        int r = row[e], c = col[e];
        int pos = rowstart[r] + atomicAdd(&fill[r], 1);
        edge_dst[pos] = c;
        edge_norm[pos] = dis[r] * dis[c];
    }
}

// ---------------- weight conversion: W[K,N] fp32 -> frag layout [Kpad/8][Npad][8] bf16 hi/lo ----------------

__global__ void convB_kernel(const float* __restrict__ W,
                             unsigned short* __restrict__ bth, unsigned short* __restrict__ btl,
                             int K, int N, int Kpad, int Npad) {
    int idx = blockIdx.x * blockDim.x + threadIdx.x;
    int total = (Kpad / 8) * Npad * 8;
    if (idx >= total) return;
    int i = idx & 7;
    int rest = idx >> 3;
    int n = rest % Npad;
    int qg = rest / Npad;
    int k = qg * 8 + i;
    float v = (k < K && n < N) ? W[k * N + n] : 0.f;
    unsigned short h = f2bf(v);
    unsigned short l = f2bf(v - bf2f(h));
    bth[idx] = h;
    btl[idx] = l;
}

// ---------------- split-bf16 MFMA GEMM ----------------
// C[M,Npad] = A[M,Kpad] @ B, A stride == Kpad (zero-padded cols where needed).
// Tile 128x64, 4 waves. Optional fused bias+relu epilogue.

__global__ __launch_bounds__(256) void mfma_gemm(const float* __restrict__ A,
                                                 const unsigned short* __restrict__ Bth,
                                                 const unsigned short* __restrict__ Btl,
                                                 float* __restrict__ C,
                                                 const float* __restrict__ bias,
                                                 int M, int Kpad, int Npad, int Nbias, int dorelu) {
    __shared__ unsigned short Ah[4 * 128 * 8];
    __shared__ unsigned short Al[4 * 128 * 8];
    const int tid  = threadIdx.x;
    const int lane = tid & 63;
    const int wid  = tid >> 6;
    const int wm   = (wid >> 1) * 64;
    const int wn   = (wid & 1) * 32;
    const int m0   = blockIdx.y * 128;
    const int n0   = blockIdx.x * 64;
    const int q    = lane >> 4;
    const int lr   = lane & 15;

    f32x4 acc[4][2];
    #pragma unroll
    for (int i = 0; i < 4; ++i)
        #pragma unroll
        for (int j = 0; j < 2; ++j) {
            f32x4 z = {0.f, 0.f, 0.f, 0.f};
            acc[i][j] = z;
        }

    f32x4 rg[4];

    auto load_tile = [&](int k0) {
        #pragma unroll
        for (int it = 0; it < 4; ++it) {
            int lin = it * 256 + tid;
            int r   = lin >> 3;
            int f4  = lin & 7;
            int row = m0 + r;
            int k   = k0 + f4 * 4;
            f32x4 v = {0.f, 0.f, 0.f, 0.f};
            if (row < M) v = *(const f32x4*)(A + (size_t)row * Kpad + k);
            rg[it] = v;
        }
    };

    auto write_stage = [&]() {
        #pragma unroll
        for (int it = 0; it < 4; ++it) {
            int lin  = it * 256 + tid;
            int r    = lin >> 3;
            int f4   = lin & 7;
            int qq   = f4 >> 1;
            int half = f4 & 1;
            u16x4 hi, lo;
            #pragma unroll
            for (int e = 0; e < 4; ++e) {
                float v = rg[it][e];
                unsigned short h = f2bf(v);
                hi[e] = h;
                lo[e] = f2bf(v - bf2f(h));
            }
            int off = (qq * 128 + r) * 8 + half * 4;
            *(u16x4*)(Ah + off) = hi;
            *(u16x4*)(Al + off) = lo;
        }
    };

    load_tile(0);
    const int nk = Kpad >> 5;
    for (int t = 0; t < nk; ++t) {
        if (t) __syncthreads();
        write_stage();
        __syncthreads();
        if (t + 1 < nk) load_tile((t + 1) * 32);

        bf16x8 ah[4], al[4];
        #pragma unroll
        for (int mf = 0; mf < 4; ++mf) {
            int off = (q * 128 + wm + mf * 16 + lr) * 8;
            ah[mf] = *(const bf16x8*)(Ah + off);
            al[mf] = *(const bf16x8*)(Al + off);
        }
        bf16x8 bh[2], bl[2];
        int qg = t * 4 + q;
        #pragma unroll
        for (int nf = 0; nf < 2; ++nf) {
            int n = n0 + wn + nf * 16 + lr;
            size_t coff = ((size_t)qg * Npad + n) * 8;
            bh[nf] = *(const bf16x8*)(Bth + coff);
            bl[nf] = *(const bf16x8*)(Btl + coff);
        }
        #pragma unroll
        for (int mf = 0; mf < 4; ++mf)
            #pragma unroll
            for (int nf = 0; nf < 2; ++nf)
                acc[mf][nf] = __builtin_amdgcn_mfma_f32_16x16x32_bf16(ah[mf], bh[nf], acc[mf][nf], 0, 0, 0);
        #pragma unroll
        for (int mf = 0; mf < 4; ++mf)
            #pragma unroll
            for (int nf = 0; nf < 2; ++nf)
                acc[mf][nf] = __builtin_amdgcn_mfma_f32_16x16x32_bf16(ah[mf], bl[nf], acc[mf][nf], 0, 0, 0);
        #pragma unroll
        for (int mf = 0; mf < 4; ++mf)
            #pragma unroll
            for (int nf = 0; nf < 2; ++nf)
                acc[mf][nf] = __builtin_amdgcn_mfma_f32_16x16x32_bf16(al[mf], bh[nf], acc[mf][nf], 0, 0, 0);
    }

    #pragma unroll
    for (int nf = 0; nf < 2; ++nf) {
        int col = n0 + wn + nf * 16 + lr;
        float bb = (bias != nullptr && col < Nbias) ? bias[col] : 0.f;
        #pragma unroll
        for (int mf = 0; mf < 4; ++mf) {
            int row_base = m0 + wm + mf * 16 + (lane >> 4) * 4;
            #pragma unroll
            for (int r = 0; r < 4; ++r) {
                int row = row_base + r;
                if (row < M) {
                    float v = acc[mf][nf][r] + bb;
                    if (dorelu) v = fmaxf(v, 0.f);
                    C[(size_t)row * Npad + col] = v;
                }
            }
        }
    }
}

// ---------------- CSR gather aggregation ----------------
// R4 = float4s per source row (src stride = R4*4 floats); EPW = edges in parallel
// per wave (R4*EPW == 64). One wave per node, 4 nodes per 256-thread block.
// Batched index staging + shfl broadcast + 4-deep load pipeline.

template <int R4, int EPW>
__global__ __launch_bounds__(256) void agg_kernel(const float* __restrict__ src,
                                                  const int* __restrict__ rowstart,
                                                  const int* __restrict__ edge_dst,
                                                  const float* __restrict__ edge_norm,
                                                  const float* __restrict__ bias,
                                                  float* __restrict__ out,
                                                  int out_stride, int fout, int dorelu,
                                                  int nnodes) {
    const int wid  = threadIdx.x >> 6;
    const int node = blockIdx.x * 4 + wid;
    if (node >= nnodes) return;
    const int lane = threadIdx.x & 63;
    const int g    = lane / R4;
    const int lg   = lane % R4;
    const int start = rowstart[node], end = rowstart[node + 1];
    const f32x4* s4 = (const f32x4*)src;
    f32x4 acc = {0.f, 0.f, 0.f, 0.f};

    for (int base = start; base < end; base += 64) {
        int nb = end - base;
        if (nb > 64) nb = 64;
        int ge = base + lane;
        int idx = (lane < nb) ? edge_dst[ge] : 0;
        float w = (lane < nb) ? edge_norm[ge] : 0.f;
        int iters = (nb + EPW - 1) / EPW;
        int j = 0;
        for (; j + 4 <= iters; j += 4) {
            int c0 = __shfl(idx, (j + 0) * EPW + g); float w0 = __shfl(w, (j + 0) * EPW + g);
            int c1 = __shfl(idx, (j + 1) * EPW + g); float w1 = __shfl(w, (j + 1) * EPW + g);
            int c2 = __shfl(idx, (j + 2) * EPW + g); float w2 = __shfl(w, (j + 2) * EPW + g);
            int c3 = __shfl(idx, (j + 3) * EPW + g); float w3 = __shfl(w, (j + 3) * EPW + g);
            f32x4 v0 = s4[(size_t)c0 * R4 + lg];
            f32x4 v1 = s4[(size_t)c1 * R4 + lg];
            f32x4 v2 = s4[(size_t)c2 * R4 + lg];
            f32x4 v3 = s4[(size_t)c3 * R4 + lg];
            acc += v0 * w0;
            acc += v1 * w1;
            acc += v2 * w2;
            acc += v3 * w3;
        }
        for (; j < iters; ++j) {
            int sl = j * EPW + g;
            int c = __shfl(idx, sl); float w0 = __shfl(w, sl);
            f32x4 v = s4[(size_t)c * R4 + lg];
            acc += v * w0;
        }
    }

    // cross-group reduction (groups hold different edges of the same node)
    #pragma unroll
    for (int d = R4; d < 64; d <<= 1) {
        #pragma unroll
        for (int k = 0; k < 4; ++k) acc[k] += __shfl_xor(acc[k], d);
    }

    if (g == 0) {
        int f0 = lg * 4;
        if (f0 < out_stride) {
            f32x4 v = acc;
            if (bias != nullptr) {
                #pragma unroll
                for (int e = 0; e < 4; ++e) {
                    int f = f0 + e;
                    if (f < fout) {
                        float t = v[e] + bias[f];
                        if (dorelu) t = fmaxf(t, 0.f);
                        v[e] = t;
                    }
                }
            }
            *(f32x4*)(out + (size_t)node * out_stride + f0) = v;
        }
    }
}

// ---------------- fused final MLP ----------------

__global__ void final_kernel(const float* __restrict__ a3,
                             const float* __restrict__ Wf1, const float* __restrict__ bf1,
                             const float* __restrict__ Wf2, const float* __restrict__ bf2,
                             float* __restrict__ out, int n, int C, int H) {
    int i = blockIdx.x * blockDim.x + threadIdx.x;
    if (i >= n) return;
    const float* xr = a3 + (size_t)i * C;
    float hbuf[16];
    for (int j = 0; j < H; ++j) hbuf[j] = bf1[j];
    for (int k = 0; k < C; ++k) {
        float xv = xr[k];
        for (int j = 0; j < H; ++j) hbuf[j] += xv * Wf1[k * H + j];
    }
    float o = bf2[0];
    for (int j = 0; j < H; ++j) o += hbuf[j] * Wf2[j];
    out[i] = o;
}

// ---------------- launch ----------------

extern "C" void kernel_launch(void* const* d_in, const int* in_sizes, int n_in,
                              void* d_out, int out_size, void* d_ws, size_t ws_size,
                              hipStream_t stream) {
    const float* x   = (const float*)d_in[0];
    const int*   ei  = (const int*)d_in[1];
    const float* W1  = (const float*)d_in[2];
    const float* b1  = (const float*)d_in[3];
    const float* W2  = (const float*)d_in[4];
    const float* b2  = (const float*)d_in[5];
    const float* W3  = (const float*)d_in[6];
    const float* b3  = (const float*)d_in[7];
    const float* Wf1 = (const float*)d_in[8];
    const float* bf1 = (const float*)d_in[9];
    const float* Wf2 = (const float*)d_in[10];
    const float* bf2 = (const float*)d_in[11];
    float* out = (float*)d_out;

    const int N    = out_size;                 // 50000
    const int E    = in_sizes[1] / 2;          // 800000
    const int IN_C = in_sizes[0] / N;          // 256
    const int H1   = in_sizes[3];              // 300
    const int H2   = in_sizes[5];              // 100
    const int OUTC = in_sizes[7];              // 32
    const int F1   = in_sizes[9];              // 16
    const int EL   = E + N;

    const int KP1 = 256, NP1 = 320;            // layer1: K=256 (=IN_C), N=300
    const int KP2 = 320, NP2 = 128;            // layer2: K=300, N=100
    const int KP3 = 128, NP3 = 64;             // layer3: K=100, N=32

    const int* row = ei;
    const int* col = ei + E;

    size_t off = 0;
    auto alloc = [&](size_t bytes) {
        size_t o = off;
        off += (bytes + 255) & ~(size_t)255;
        return o;
    };
    char* ws = (char*)d_ws;
    int*   cnt      = (int*)  (ws + alloc((size_t)N * 4));
    int*   fill     = (int*)  (ws + alloc((size_t)N * 4));
    float* dis      = (float*)(ws + alloc((size_t)N * 4));
    int*   rowstart = (int*)  (ws + alloc((size_t)(N + 1) * 4));
    int*   edge_dst = (int*)  (ws + alloc((size_t)EL * 4));
    float* edge_nrm = (float*)(ws + alloc((size_t)EL * 4));
    unsigned short* Bt1h = (unsigned short*)(ws + alloc((size_t)(KP1/8) * NP1 * 8 * 2));
    unsigned short* Bt1l = (unsigned short*)(ws + alloc((size_t)(KP1/8) * NP1 * 8 * 2));
    unsigned short* Bt2h = (unsigned short*)(ws + alloc((size_t)(KP2/8) * NP2 * 8 * 2));
    unsigned short* Bt2l = (unsigned short*)(ws + alloc((size_t)(KP2/8) * NP2 * 8 * 2));
    unsigned short* Bt3h = (unsigned short*)(ws + alloc((size_t)(KP3/8) * NP3 * 8 * 2));
    unsigned short* Bt3l = (unsigned short*)(ws + alloc((size_t)(KP3/8) * NP3 * 8 * 2));
    float* bufA = (float*)(ws + alloc((size_t)N * KP1 * 4));   // 51.2 MB: agg_x; later h2+a2
    float* bufB = (float*)(ws + alloc((size_t)N * NP1 * 4));   // 64 MB: a1; later h3+a3

    float* agg_x = bufA;                         // [N,256]
    float* a1    = bufB;                         // [N,320]
    float* h2    = bufA;                         // [N,128]
    float* a2    = bufA + (size_t)N * NP2;       // [N,128]
    float* h3    = bufB;                         // [N,64]  (a1 dead after GEMM2)
    float* a3    = bufB + (size_t)N * NP3;       // [N,32]
    // NOTE: h3/a3 overwrite a1's buffer only after a1 is consumed by GEMM2.

    const int gN = (N + WG - 1) / WG;
    const int gE = (E + WG - 1) / WG;
    const int gAgg = (N + 3) / 4;

    // --- build CSR ---
    hipMemsetAsync(cnt, 0, (size_t)N * 4, stream);
    count_kernel<<<gE, WG, 0, stream>>>(row, cnt, E);
    dis_kernel<<<gN, WG, 0, stream>>>(cnt, dis, N);
    scan_kernel<<<1, 1024, 0, stream>>>(cnt, rowstart, N);
    selfloop_kernel<<<gN, WG, 0, stream>>>(rowstart, dis, edge_dst, edge_nrm, fill, N);
    scatter_kernel<<<gE, WG, 0, stream>>>(row, col, rowstart, dis, edge_dst, edge_nrm, fill, E);

    // --- convert weights ---
    {
        int t1 = (KP1/8) * NP1 * 8;
        convB_kernel<<<(t1 + WG - 1) / WG, WG, 0, stream>>>(W1, Bt1h, Bt1l, IN_C, H1, KP1, NP1);
        int t2 = (KP2/8) * NP2 * 8;
        convB_kernel<<<(t2 + WG - 1) / WG, WG, 0, stream>>>(W2, Bt2h, Bt2l, H1, H2, KP2, NP2);
        int t3 = (KP3/8) * NP3 * 8;
        convB_kernel<<<(t3 + WG - 1) / WG, WG, 0, stream>>>(W3, Bt3h, Bt3l, H2, OUTC, KP3, NP3);
    }

    const int MB = (N + 127) / 128;

    // --- layer 1: agg first (X has 256 feats), then GEMM with fused bias+relu ---
    agg_kernel<64, 1><<<gAgg, WG, 0, stream>>>(x, rowstart, edge_dst, edge_nrm,
                                               nullptr, agg_x, KP1, KP1, 0, N);
    mfma_gemm<<<dim3(NP1 / 64, MB), 256, 0, stream>>>(agg_x, Bt1h, Bt1l, a1, b1,
                                                      N, KP1, NP1, H1, 1);
    // --- layer 2: GEMM, then agg (100 out-feats < 300 in-feats) ---
    mfma_gemm<<<dim3(NP2 / 64, MB), 256, 0, stream>>>(a1, Bt2h, Bt2l, h2, nullptr,
                                                      N, KP2, NP2, 0, 0);
    agg_kernel<32, 2><<<gAgg, WG, 0, stream>>>(h2, rowstart, edge_dst, edge_nrm,
                                               b2, a2, NP2, H2, 1, N);
    // --- layer 3 ---
    mfma_gemm<<<dim3(NP3 / 64, MB), 256, 0, stream>>>(a2, Bt3h, Bt3l, h3, nullptr,
                                                      N, KP3, NP3, 0, 0);
    agg_kernel<16, 4><<<gAgg, WG, 0, stream>>>(h3, rowstart, edge_dst, edge_nrm,
                                               b3, a3, OUTC, OUTC, 1, N);
    // --- final MLP ---
    final_kernel<<<gN, WG, 0, stream>>>(a3, Wf1, bf1, Wf2, bf2, out, N, OUTC, F1);
}